// Round 5
// baseline (131.424 us; speedup 1.0000x reference)
//
#include <hip/hip_runtime.h>

#define TLEN 2048
#define BROWS 8192
#define W 8
#define WPB 16                    // waves (rows) per block
#define NBLK (BROWS / WPB)        // 512 blocks x 1024 threads = 8192 waves (full machine)
#define POISON_U32 0xAAAAAAAAu    // harness re-poisons d_ws to 0xAA before every launch

__global__ __launch_bounds__(1024) void
loss_fused_kernel(const float* __restrict__ outputs,
                  const int* __restrict__ labels,
                  unsigned int* __restrict__ counter,
                  float* __restrict__ partials,
                  float* __restrict__ out) {
    const int tid  = threadIdx.x;
    const int wave = tid >> 6;        // 0..15
    const int lane = tid & 63;
    const int row  = blockIdx.x * WPB + wave;

    const float* __restrict__ orow = outputs + (size_t)row * TLEN;
    const int*   __restrict__ lrow = labels  + (size_t)row * TLEN;

    // issue BOTH first-chunk loads up front — one memory round-trip
    const int   lab = lrow[lane];
    const float p   = orow[lane];

    const int lab0 = __shfl(lab, 0, 64);
    const unsigned long long m0 = __ballot(lab != lab0);
    const int ind0f = m0 ? (__ffsll(m0) - 1) : -1;

    float per_sample;

    if (m0 && ind0f + W <= 64) {
        // ======== fast path (P ≈ 1 - 2^-57 per row): all in-register ========
        const int ind0 = ind0f;
        const bool act = lane < ind0;
        const float pe = act ? p : 0.0f;
        float incl = act ? (1.0f - p) : 1.0f;
        #pragma unroll
        for (int off = 1; off < 64; off <<= 1) {
            float o = __shfl_up(incl, off, 64);
            if (lane >= off) incl *= o;
        }
        float excl = __shfl_up(incl, 1, 64);
        if (lane == 0) excl = 1.0f;
        float term = (float)(lane + 1) * pe * excl;
        #pragma unroll
        for (int off = 32; off; off >>= 1) term += __shfl_xor(term, off, 64);
        const float fa = 1.0f - term;

        // window: n = 8 always here (ind0 <= 56)
        float cp = 1.0f, term1 = 0.0f, cpl = 1.0f, pl = 0.0f;
        #pragma unroll
        for (int k = 0; k < W; ++k) {
            float pk = __shfl(p, ind0 + k, 64);
            term1 += (float)(k + 1) * pk * cp;
            cpl = cp; pl = pk;
            cp *= (1.0f - pk);
        }
        const float dd = term1 + (float)W * (float)(W + 1) * cpl * (1.0f - pl);
        per_sample = 0.5f * (dd + fa);       // ALPHA = 0.5
    } else {
        // ======== slow path (correctness only; ~never taken) ========
        int ind0 = -1;
        for (int base = 0; base < TLEN; base += 64) {
            int lb = (base == 0) ? lab : lrow[base + lane];
            unsigned long long m = __ballot(lb != lab0);
            if (m) { ind0 = base + __ffsll(m) - 1; break; }
        }
        const bool has_change = (ind0 >= 0);
        const int L = has_change ? ind0 : TLEN;

        float S = 0.0f, carry = 1.0f;
        for (int base = 0; base < L && carry != 0.0f; base += 64) {
            const int k = base + lane;
            const bool act = (k < L);
            const float pk = act ? orow[k] : 0.0f;
            float incl = act ? (1.0f - pk) : 1.0f;
            #pragma unroll
            for (int off = 1; off < 64; off <<= 1) {
                float o = __shfl_up(incl, off, 64);
                if (lane >= off) incl *= o;
            }
            float excl = __shfl_up(incl, 1, 64);
            if (lane == 0) excl = 1.0f;
            float term = act ? ((float)(k + 1) * pk * carry * excl) : 0.0f;
            #pragma unroll
            for (int off = 32; off; off >>= 1) term += __shfl_xor(term, off, 64);
            S += term;
            carry *= __shfl(incl, 63, 64);   // once 0, all remaining ref terms are exactly 0
        }
        const float fa = 1.0f - S;

        per_sample = fa;
        if (has_change) {
            float pw = 0.0f;
            const int idx = ind0 + lane;
            if (lane < W && idx < TLEN) pw = orow[idx];
            const int n = min(W, TLEN - ind0);
            float cp = 1.0f, term1 = 0.0f, cpl = 1.0f, pl = 0.0f;
            #pragma unroll
            for (int k = 0; k < W; ++k) {
                if (k < n) {
                    float pk = __shfl(pw, k, 64);
                    term1 += (float)(k + 1) * pk * cp;
                    cpl = cp; pl = pk;
                    cp *= (1.0f - pk);
                }
            }
            const float dd = term1 + (float)n * (float)(W + 1) * cpl * (1.0f - pl);
            per_sample = 0.5f * dd + 0.5f * fa;
        }
    }

    // ---- block partial ----
    __shared__ float sred[WPB];
    __shared__ bool s_last;
    if (lane == 0) sred[wave] = per_sample;
    __syncthreads();
    if (tid == 0) {
        float s = 0.0f;
        #pragma unroll
        for (int i = 0; i < WPB; ++i) s += sred[i];
        atomicExch(&partials[blockIdx.x], s);       // device-scope atomic store
        __threadfence();                            // release
        unsigned int old = atomicAdd(counter, 1u);
        // counter starts at harness poison (0xAAAAAAAA); tolerate 0-init too.
        s_last = (old == POISON_U32 + (NBLK - 1u)) || (old == NBLK - 1u);
    }
    __syncthreads();

    // ---- last block reduces all partials and writes the scalar ----
    if (s_last) {
        __threadfence();                            // acquire
        float s = 0.0f;
        if (tid < NBLK) s = atomicAdd(&partials[tid], 0.0f);  // coherent read
        #pragma unroll
        for (int off = 32; off; off >>= 1) s += __shfl_xor(s, off, 64);
        __shared__ float sr2[WPB];
        if (lane == 0) sr2[wave] = s;
        __syncthreads();
        if (tid == 0) {
            float t = 0.0f;
            #pragma unroll
            for (int i = 0; i < WPB; ++i) t += sr2[i];
            out[0] = t * (1.0f / (float)BROWS);
        }
    }
}

extern "C" void kernel_launch(void* const* d_in, const int* in_sizes, int n_in,
                              void* d_out, int out_size, void* d_ws, size_t ws_size,
                              hipStream_t stream) {
    const float* outputs = (const float*)d_in[0];
    const int*   labels  = (const int*)d_in[1];
    float* out = (float*)d_out;

    unsigned int* counter = (unsigned int*)d_ws;                 // [0]
    float* partials = (float*)((char*)d_ws + 256);               // 512 floats, fully overwritten

    loss_fused_kernel<<<NBLK, 1024, 0, stream>>>(outputs, labels, counter, partials, out);
}

// Round 6
// 120.465 us; speedup vs baseline: 1.0910x; 1.0910x over previous
//
#include <hip/hip_runtime.h>

#define TLEN 2048
#define BROWS 8192
#define W 8
#define NBLK (BROWS / 4)   // 2048 blocks, 4 waves (rows) each

__global__ __launch_bounds__(256) void
loss_rows_kernel(const float* __restrict__ outputs,
                 const int* __restrict__ labels,
                 float* __restrict__ partials) {
    const int wave = threadIdx.x >> 6;       // 0..3
    const int lane = threadIdx.x & 63;
    const int row  = blockIdx.x * 4 + wave;

    const float* __restrict__ orow = outputs + (size_t)row * TLEN;
    const int*   __restrict__ lrow = labels  + (size_t)row * TLEN;

    // issue BOTH first-chunk loads up front — one memory round-trip
    const int   lab = lrow[lane];
    const float p   = orow[lane];

    const int lab0 = __shfl(lab, 0, 64);
    const unsigned long long m0 = __ballot(lab != lab0);
    const int ind0f = m0 ? (__ffsll(m0) - 1) : -1;

    float per_sample;

    if (m0 && ind0f + W <= 64) {
        // ======== fast path (P ≈ 1 - 2^-57 per row): all in-register ========
        const int ind0 = ind0f;
        const bool act = lane < ind0;
        const float pe = act ? p : 0.0f;
        float incl = act ? (1.0f - p) : 1.0f;
        #pragma unroll
        for (int off = 1; off < 64; off <<= 1) {
            float o = __shfl_up(incl, off, 64);
            if (lane >= off) incl *= o;
        }
        float excl = __shfl_up(incl, 1, 64);
        if (lane == 0) excl = 1.0f;
        float term = (float)(lane + 1) * pe * excl;
        #pragma unroll
        for (int off = 32; off; off >>= 1) term += __shfl_xor(term, off, 64);
        const float fa = 1.0f - term;

        // window: n = 8 always here (ind0 <= 56)
        float cp = 1.0f, term1 = 0.0f, cpl = 1.0f, pl = 0.0f;
        #pragma unroll
        for (int k = 0; k < W; ++k) {
            float pk = __shfl(p, ind0 + k, 64);
            term1 += (float)(k + 1) * pk * cp;
            cpl = cp; pl = pk;
            cp *= (1.0f - pk);
        }
        const float dd = term1 + (float)W * (float)(W + 1) * cpl * (1.0f - pl);
        per_sample = 0.5f * (dd + fa);       // ALPHA = 0.5
    } else {
        // ======== slow path (correctness only; ~never taken) ========
        int ind0 = -1;
        for (int base = 0; base < TLEN; base += 64) {
            int lb = (base == 0) ? lab : lrow[base + lane];
            unsigned long long m = __ballot(lb != lab0);
            if (m) { ind0 = base + __ffsll(m) - 1; break; }
        }
        const bool has_change = (ind0 >= 0);
        const int L = has_change ? ind0 : TLEN;

        float S = 0.0f, carry = 1.0f;
        for (int base = 0; base < L && carry != 0.0f; base += 64) {
            const int k = base + lane;
            const bool act = (k < L);
            const float pk = act ? orow[k] : 0.0f;
            float incl = act ? (1.0f - pk) : 1.0f;
            #pragma unroll
            for (int off = 1; off < 64; off <<= 1) {
                float o = __shfl_up(incl, off, 64);
                if (lane >= off) incl *= o;
            }
            float excl = __shfl_up(incl, 1, 64);
            if (lane == 0) excl = 1.0f;
            float term = act ? ((float)(k + 1) * pk * carry * excl) : 0.0f;
            #pragma unroll
            for (int off = 32; off; off >>= 1) term += __shfl_xor(term, off, 64);
            S += term;
            carry *= __shfl(incl, 63, 64);   // once 0, all remaining ref terms are exactly 0
        }
        const float fa = 1.0f - S;

        per_sample = fa;
        if (has_change) {
            float pw = 0.0f;
            const int idx = ind0 + lane;
            if (lane < W && idx < TLEN) pw = orow[idx];
            const int n = min(W, TLEN - ind0);
            float cp = 1.0f, term1 = 0.0f, cpl = 1.0f, pl = 0.0f;
            #pragma unroll
            for (int k = 0; k < W; ++k) {
                if (k < n) {
                    float pk = __shfl(pw, k, 64);
                    term1 += (float)(k + 1) * pk * cp;
                    cpl = cp; pl = pk;
                    cp *= (1.0f - pk);
                }
            }
            const float dd = term1 + (float)n * (float)(W + 1) * cpl * (1.0f - pl);
            per_sample = 0.5f * dd + 0.5f * fa;
        }
    }

    // per-block partial -> d_ws (fully overwritten, no init needed)
    __shared__ float sred[4];
    if (lane == 0) sred[wave] = per_sample;
    __syncthreads();
    if (threadIdx.x == 0)
        partials[blockIdx.x] = sred[0] + sred[1] + sred[2] + sred[3];
}

__global__ __launch_bounds__(256) void
loss_reduce_kernel(const float* __restrict__ partials,
                   float* __restrict__ out) {
    const int tid = threadIdx.x;
    float s = 0.0f;
    #pragma unroll
    for (int i = 0; i < NBLK / 256; ++i) s += partials[tid + i * 256];
    #pragma unroll
    for (int off = 32; off; off >>= 1) s += __shfl_xor(s, off, 64);
    __shared__ float sr[4];
    if ((tid & 63) == 0) sr[tid >> 6] = s;
    __syncthreads();
    if (tid == 0) out[0] = (sr[0] + sr[1] + sr[2] + sr[3]) * (1.0f / (float)BROWS);
}

extern "C" void kernel_launch(void* const* d_in, const int* in_sizes, int n_in,
                              void* d_out, int out_size, void* d_ws, size_t ws_size,
                              hipStream_t stream) {
    const float* outputs = (const float*)d_in[0];
    const int*   labels  = (const int*)d_in[1];
    float* out      = (float*)d_out;
    float* partials = (float*)d_ws;          // NBLK floats of scratch

    loss_rows_kernel<<<NBLK, 256, 0, stream>>>(outputs, labels, partials);
    loss_reduce_kernel<<<1, 256, 0, stream>>>(partials, out);
}